// Round 1
// baseline (711.032 us; speedup 1.0000x reference)
//
#include <hip/hip_runtime.h>
#include <math.h>

#define NBATCH 8
#define NPTS   2048
#define BLK    256
#define BLKS_PER_BATCH (NPTS / BLK)   // 8
#define TOLF 1e-4f
#define EPSF 1e-12f

// ---------------- deterministic block reduction of 16 doubles ----------------
__device__ inline void block_reduce_store16(double v[16], double* dst) {
    __shared__ double red[4][16];
    int lane = threadIdx.x & 63;
    int wv   = threadIdx.x >> 6;
#pragma unroll
    for (int k = 0; k < 16; ++k) {
        double x = v[k];
#pragma unroll
        for (int off = 32; off > 0; off >>= 1) x += __shfl_down(x, off);
        if (lane == 0) red[wv][k] = x;
    }
    __syncthreads();
    if (threadIdx.x == 0) {
#pragma unroll
        for (int k = 0; k < 16; ++k)
            dst[k] = red[0][k] + red[1][k] + red[2][k] + red[3][k];
    }
}

// ---------------- init workspace ----------------
__global__ __launch_bounds__(256) void init_ws(const float* __restrict__ psrc,
                                               float* __restrict__ pc,
                                               float* __restrict__ err,
                                               int* __restrict__ done) {
    int g = blockIdx.x * blockDim.x + threadIdx.x;
    int total = NBATCH * NPTS * 3;
    for (int f = g; f < total; f += gridDim.x * blockDim.x) pc[f] = psrc[f];
    if (g < NBATCH) err[g] = 0.0f;
    if (g == NBATCH) *done = 0;
}

// ---------------- NN search + H/centroid/err accumulation ----------------
// grid: NBATCH * BLKS_PER_BATCH blocks of 256; one src point per thread.
__global__ __launch_bounds__(256) void nn_acc(const float* __restrict__ ptgt,
                                              const float* __restrict__ pc,
                                              double* __restrict__ part,
                                              const int* __restrict__ done) {
    if (*done) return;
    int b     = blockIdx.x >> 3;
    int chunk = blockIdx.x & 7;
    int tid   = threadIdx.x;

    __shared__ float4 tg[NPTS];   // (x, y, z, 0.5*|t|^2)  32KB

    const float* tb = ptgt + b * NPTS * 3;
    for (int f = tid; f < NPTS * 3; f += BLK) {
        int j = f / 3, c = f - 3 * j;
        ((float*)&tg[j])[c] = tb[f];
    }
    __syncthreads();
    for (int j = tid; j < NPTS; j += BLK) {
        float4 t = tg[j];
        tg[j].w = 0.5f * (t.x * t.x + t.y * t.y + t.z * t.z);
    }
    __syncthreads();

    int i = chunk * BLK + tid;
    const float* ps = pc + (b * NPTS + i) * 3;
    float x = ps[0], y = ps[1], z = ps[2];
    float a2 = x * x + y * y + z * z;

    float smin = INFINITY;
    int jmin = 0;
#pragma unroll 4
    for (int j = 0; j < NPTS; ++j) {
        float4 t = tg[j];
        float sc = t.w;
        sc = fmaf(-x, t.x, sc);
        sc = fmaf(-y, t.y, sc);
        sc = fmaf(-z, t.z, sc);
        if (sc < smin) { smin = sc; jmin = j; }
    }
    float4 q = tg[jmin];
    float d2 = fmaf(2.0f, smin, a2);
    float dist = sqrtf(fmaxf(d2, EPSF));

    double v[16];
    v[0] = dist;
    v[1] = x;  v[2] = y;  v[3] = z;
    v[4] = q.x; v[5] = q.y; v[6] = q.z;
    v[7]  = (double)x * q.x; v[8]  = (double)x * q.y; v[9]  = (double)x * q.z;
    v[10] = (double)y * q.x; v[11] = (double)y * q.y; v[12] = (double)y * q.z;
    v[13] = (double)z * q.x; v[14] = (double)z * q.y; v[15] = (double)z * q.z;

    block_reduce_store16(v, part + (b * 8 + chunk) * 16);
}

// ---------------- accumulation for the final Kabsch (psrc -> pc) ----------------
__global__ __launch_bounds__(256) void final_acc(const float* __restrict__ psrc,
                                                 const float* __restrict__ pc,
                                                 double* __restrict__ part) {
    int b     = blockIdx.x >> 3;
    int chunk = blockIdx.x & 7;
    int i = chunk * BLK + threadIdx.x;
    const float* p = psrc + (b * NPTS + i) * 3;
    const float* q = pc   + (b * NPTS + i) * 3;
    float x = p[0], y = p[1], z = p[2];
    float qx = q[0], qy = q[1], qz = q[2];

    double v[16];
    v[0] = 0.0;
    v[1] = x;  v[2] = y;  v[3] = z;
    v[4] = qx; v[5] = qy; v[6] = qz;
    v[7]  = (double)x * qx; v[8]  = (double)x * qy; v[9]  = (double)x * qz;
    v[10] = (double)y * qx; v[11] = (double)y * qy; v[12] = (double)y * qz;
    v[13] = (double)z * qx; v[14] = (double)z * qy; v[15] = (double)z * qz;

    block_reduce_store16(v, part + (b * 8 + chunk) * 16);
}

// ---------------- 3x3 Kabsch (double, one-sided Jacobi SVD) ----------------
__device__ void kabsch3x3(const double Spq[9], const double Sp[3], const double Sq[3],
                          double R[9], double t[3]) {
    const double invN = 1.0 / (double)NPTS;
    double cs[3], ct[3];
#pragma unroll
    for (int i = 0; i < 3; ++i) { cs[i] = Sp[i] * invN; ct[i] = Sq[i] * invN; }
    double H[9];
#pragma unroll
    for (int i = 0; i < 3; ++i)
#pragma unroll
        for (int j = 0; j < 3; ++j)
            H[i * 3 + j] = Spq[i * 3 + j] - (double)NPTS * cs[i] * ct[j];

    // one-sided Jacobi on columns of H; Bc/V stored column-major [col][row]
    double Bc[3][3], V[3][3];
#pragma unroll
    for (int j = 0; j < 3; ++j)
#pragma unroll
        for (int i = 0; i < 3; ++i) {
            Bc[j][i] = H[i * 3 + j];
            V[j][i]  = (i == j) ? 1.0 : 0.0;
        }
    for (int sweep = 0; sweep < 30; ++sweep) {
        bool rotated = false;
        for (int p = 0; p < 2; ++p)
            for (int q = p + 1; q < 3; ++q) {
                double app = 0, aqq = 0, apq = 0;
#pragma unroll
                for (int i = 0; i < 3; ++i) {
                    app += Bc[p][i] * Bc[p][i];
                    aqq += Bc[q][i] * Bc[q][i];
                    apq += Bc[p][i] * Bc[q][i];
                }
                if (apq * apq > 1e-60 + 1e-28 * app * aqq) {
                    rotated = true;
                    double tau = (aqq - app) / (2.0 * apq);
                    double tt  = (tau >= 0 ? 1.0 : -1.0) / (fabs(tau) + sqrt(1.0 + tau * tau));
                    double c   = 1.0 / sqrt(1.0 + tt * tt);
                    double sn  = c * tt;
#pragma unroll
                    for (int i = 0; i < 3; ++i) {
                        double bp = Bc[p][i], bq = Bc[q][i];
                        Bc[p][i] = c * bp - sn * bq;
                        Bc[q][i] = sn * bp + c * bq;
                        double vp = V[p][i], vq = V[q][i];
                        V[p][i] = c * vp - sn * vq;
                        V[q][i] = sn * vp + c * vq;
                    }
                }
            }
        if (!rotated) break;
    }
    double sv[3], U[3][3];
#pragma unroll
    for (int j = 0; j < 3; ++j) {
        sv[j] = sqrt(Bc[j][0] * Bc[j][0] + Bc[j][1] * Bc[j][1] + Bc[j][2] * Bc[j][2]);
        double inv = sv[j] > 0.0 ? 1.0 / sv[j] : 0.0;
#pragma unroll
        for (int i = 0; i < 3; ++i) U[j][i] = Bc[j][i] * inv;
    }
    double detH = H[0] * (H[4] * H[8] - H[5] * H[7])
                - H[1] * (H[3] * H[8] - H[5] * H[6])
                + H[2] * (H[3] * H[7] - H[4] * H[6]);
    double d = (detH >= 0.0) ? 1.0 : -1.0;
    int o[3] = {0, 1, 2};
    if (sv[o[0]] < sv[o[1]]) { int tmp = o[0]; o[0] = o[1]; o[1] = tmp; }
    if (sv[o[0]] < sv[o[2]]) { int tmp = o[0]; o[0] = o[2]; o[2] = tmp; }
    if (sv[o[1]] < sv[o[2]]) { int tmp = o[1]; o[1] = o[2]; o[2] = tmp; }
    double sg[3] = {1.0, 1.0, d};
#pragma unroll
    for (int i = 0; i < 3; ++i)
#pragma unroll
        for (int j = 0; j < 3; ++j) {
            double acc = 0.0;
#pragma unroll
            for (int k = 0; k < 3; ++k) acc += sg[k] * V[o[k]][i] * U[o[k]][j];
            R[i * 3 + j] = acc;
        }
#pragma unroll
    for (int i = 0; i < 3; ++i)
        t[i] = ct[i] - (R[i * 3 + 0] * cs[0] + R[i * 3 + 1] * cs[1] + R[i * 3 + 2] * cs[2]);
}

// ---------------- per-iteration Kabsch + convergence logic (1 wave) ----------------
__global__ __launch_bounds__(64) void kabsch_iter(const double* __restrict__ part,
                                                  float* __restrict__ err,
                                                  int* __restrict__ done,
                                                  float* __restrict__ Rt) {
    int b = threadIdx.x;
    int done_old = *done;
    double s[16];
    float errnew = 0.0f;
    if (b < NBATCH) {
#pragma unroll
        for (int k = 0; k < 16; ++k) {
            double a = 0.0;
            for (int c = 0; c < 8; ++c) a += part[(b * 8 + c) * 16 + k];
            s[k] = a;
        }
        errnew = (float)(s[0] * (1.0 / (double)NPTS));
    }
    bool conv = true;
    if (b < NBATCH) conv = fabsf(errnew - err[b]) < TOLF;
    unsigned long long m = __ballot(conv);
    bool all_conv = ((m & 0xFFull) == 0xFFull);
    int done_new = done_old | (all_conv ? 1 : 0);
    if (threadIdx.x == 0) *done = done_new;
    if (done_new) return;
    if (b < NBATCH) {
        err[b] = errnew;
        double R[9], t[3];
        kabsch3x3(&s[7], &s[1], &s[4], R, t);
        float* rt = Rt + b * 12;
#pragma unroll
        for (int k = 0; k < 9; ++k) rt[k] = (float)R[k];
#pragma unroll
        for (int k = 0; k < 3; ++k) rt[9 + k] = (float)t[k];
    }
}

// ---------------- final Kabsch -> d_out [B,3,4] ----------------
__global__ __launch_bounds__(64) void kabsch_final(const double* __restrict__ part,
                                                   float* __restrict__ out) {
    int b = threadIdx.x;
    if (b >= NBATCH) return;
    double s[16];
#pragma unroll
    for (int k = 0; k < 16; ++k) {
        double a = 0.0;
        for (int c = 0; c < 8; ++c) a += part[(b * 8 + c) * 16 + k];
        s[k] = a;
    }
    double R[9], t[3];
    kabsch3x3(&s[7], &s[1], &s[4], R, t);
    float* o = out + b * 12;
#pragma unroll
    for (int i = 0; i < 3; ++i) {
#pragma unroll
        for (int j = 0; j < 3; ++j) o[i * 4 + j] = (float)R[i * 3 + j];
        o[i * 4 + 3] = (float)t[i];
    }
}

// ---------------- apply rigid update ----------------
__global__ __launch_bounds__(256) void update_pc(float* __restrict__ pc,
                                                 const float* __restrict__ Rt,
                                                 const int* __restrict__ done) {
    if (*done) return;
    int g = blockIdx.x * blockDim.x + threadIdx.x;   // 0..16383
    int b = g >> 11;
    const float* rt = Rt + b * 12;
    float* p = pc + g * 3;
    float x = p[0], y = p[1], z = p[2];
    p[0] = rt[0] * x + rt[1] * y + rt[2] * z + rt[9];
    p[1] = rt[3] * x + rt[4] * y + rt[5] * z + rt[10];
    p[2] = rt[6] * x + rt[7] * y + rt[8] * z + rt[11];
}

extern "C" void kernel_launch(void* const* d_in, const int* in_sizes, int n_in,
                              void* d_out, int out_size, void* d_ws, size_t ws_size,
                              hipStream_t stream) {
    const float* psrc = (const float*)d_in[0];
    const float* ptgt = (const float*)d_in[1];
    float* out = (float*)d_out;

    char* ws = (char*)d_ws;
    // layout: part (8KB doubles) | pc (192KB f32) | err (32B) | Rt (384B) | done (4B)
    double* part = (double*)ws;                              // 8*8*16 doubles = 8192B
    float*  pc   = (float*)(ws + 8192);                      // 8*2048*3 f32  = 196608B
    float*  err  = (float*)(ws + 8192 + 196608);             // 8 f32
    float*  Rt   = (float*)(ws + 8192 + 196608 + 32);        // 8*12 f32
    int*    done = (int*)(ws + 8192 + 196608 + 32 + 384);

    const int nblocks = NBATCH * BLKS_PER_BATCH;             // 64

    init_ws<<<64, 256, 0, stream>>>(psrc, pc, err, done);

    for (int it = 0; it < 10; ++it) {
        nn_acc<<<nblocks, BLK, 0, stream>>>(ptgt, pc, part, done);
        kabsch_iter<<<1, 64, 0, stream>>>(part, err, done, Rt);
        update_pc<<<nblocks, BLK, 0, stream>>>(pc, Rt, done);
    }

    final_acc<<<nblocks, BLK, 0, stream>>>(psrc, pc, part);
    kabsch_final<<<1, 64, 0, stream>>>(part, out);
}

// Round 2
// 375.481 us; speedup vs baseline: 1.8937x; 1.8937x over previous
//
#include <hip/hip_runtime.h>
#include <math.h>

#define NBATCH 8
#define NPTS   2048
#define BLK    256
#define BLKS_PER_BATCH (NPTS / BLK)   // 8
#define NCH    32                     // target chunks per batch
#define CH     (NPTS / NCH)           // 64 targets per chunk
#define SPT    (NPTS / BLK)           // 8 src points per thread
#define TOLF 1e-4f
#define EPSF 1e-12f

// ---------------- deterministic block reduction of 16 doubles ----------------
__device__ inline void block_reduce_store16(double v[16], double* dst) {
    __shared__ double red[4][16];
    int lane = threadIdx.x & 63;
    int wv   = threadIdx.x >> 6;
#pragma unroll
    for (int k = 0; k < 16; ++k) {
        double x = v[k];
#pragma unroll
        for (int off = 32; off > 0; off >>= 1) x += __shfl_down(x, off);
        if (lane == 0) red[wv][k] = x;
    }
    __syncthreads();
    if (threadIdx.x == 0) {
#pragma unroll
        for (int k = 0; k < 16; ++k)
            dst[k] = red[0][k] + red[1][k] + red[2][k] + red[3][k];
    }
}

// ---------------- init workspace ----------------
__global__ __launch_bounds__(256) void init_ws(const float* __restrict__ psrc,
                                               float* __restrict__ pc,
                                               float* __restrict__ err,
                                               int* __restrict__ done) {
    int g = blockIdx.x * blockDim.x + threadIdx.x;
    int total = NBATCH * NPTS * 3;
    for (int f = g; f < total; f += gridDim.x * blockDim.x) pc[f] = psrc[f];
    if (g < NBATCH) err[g] = 0.0f;
    if (g == NBATCH) *done = 0;
}

// ---------------- NN search: per-(batch, tgt-chunk) block ----------------
// grid: NBATCH * NCH = 256 blocks of 256 threads.
// Each thread owns SPT=8 src points (strided by 256); scans CH=64 targets
// staged in LDS; writes per-chunk winner (d2, idx) to pd.
__global__ __launch_bounds__(256) void nn_acc(const float* __restrict__ ptgt,
                                              const float* __restrict__ pc,
                                              float2* __restrict__ pd,
                                              const int* __restrict__ done) {
    if (*done) return;
    int b   = blockIdx.x >> 5;        // / NCH
    int ch  = blockIdx.x & (NCH - 1);
    int tid = threadIdx.x;

    __shared__ float4 tg[CH];         // (x, y, z, 0.5*|t|^2)  1KB
    const float* tb = ptgt + (b * NPTS + ch * CH) * 3;
    if (tid < CH) {
        float tx = tb[tid * 3 + 0];
        float ty = tb[tid * 3 + 1];
        float tz = tb[tid * 3 + 2];
        tg[tid] = make_float4(tx, ty, tz, 0.5f * (tx * tx + ty * ty + tz * tz));
    }
    __syncthreads();

    const float* pb = pc + b * NPTS * 3;
    float sx[SPT], sy[SPT], sz[SPT], smin[SPT];
    int jmin[SPT];
#pragma unroll
    for (int k = 0; k < SPT; ++k) {
        int s = k * BLK + tid;
        sx[k] = pb[s * 3 + 0];
        sy[k] = pb[s * 3 + 1];
        sz[k] = pb[s * 3 + 2];
        smin[k] = INFINITY;
        jmin[k] = 0;
    }

    int jbase = ch * CH;
#pragma unroll 4
    for (int j = 0; j < CH; ++j) {
        float4 t = tg[j];
        int jg = jbase + j;
#pragma unroll
        for (int k = 0; k < SPT; ++k) {
            float sc = t.w;
            sc = fmaf(-sx[k], t.x, sc);
            sc = fmaf(-sy[k], t.y, sc);
            sc = fmaf(-sz[k], t.z, sc);
            if (sc < smin[k]) { smin[k] = sc; jmin[k] = jg; }
        }
    }

    float2* out = pd + (b * NCH + ch) * NPTS;
#pragma unroll
    for (int k = 0; k < SPT; ++k) {
        int s = k * BLK + tid;
        float a2 = sx[k] * sx[k] + sy[k] * sy[k] + sz[k] * sz[k];
        float d2 = fmaf(2.0f, smin[k], a2);
        out[s] = make_float2(d2, __int_as_float(jmin[k]));
    }
}

// ---------------- cross-chunk argmin + H/centroid/err accumulation ----------------
// grid: NBATCH * BLKS_PER_BATCH = 64 blocks of 256; one src point per thread.
__global__ __launch_bounds__(256) void gather_acc(const float* __restrict__ ptgt,
                                                  const float* __restrict__ pc,
                                                  const float2* __restrict__ pd,
                                                  double* __restrict__ part,
                                                  const int* __restrict__ done) {
    if (*done) return;
    int b     = blockIdx.x >> 3;
    int chunk = blockIdx.x & 7;
    int s = chunk * BLK + threadIdx.x;

    const float2* pdb = pd + b * NCH * NPTS + s;
    float best = INFINITY;
    int bidx = 0;
#pragma unroll 8
    for (int ch = 0; ch < NCH; ++ch) {
        float2 e = pdb[ch * NPTS];
        if (e.x < best) { best = e.x; bidx = __float_as_int(e.y); }
    }
    float dist = sqrtf(fmaxf(best, EPSF));

    const float* q = ptgt + (b * NPTS + bidx) * 3;
    float qx = q[0], qy = q[1], qz = q[2];
    const float* p = pc + (b * NPTS + s) * 3;
    float x = p[0], y = p[1], z = p[2];

    double v[16];
    v[0] = dist;
    v[1] = x;  v[2] = y;  v[3] = z;
    v[4] = qx; v[5] = qy; v[6] = qz;
    v[7]  = (double)x * qx; v[8]  = (double)x * qy; v[9]  = (double)x * qz;
    v[10] = (double)y * qx; v[11] = (double)y * qy; v[12] = (double)y * qz;
    v[13] = (double)z * qx; v[14] = (double)z * qy; v[15] = (double)z * qz;

    block_reduce_store16(v, part + (b * 8 + chunk) * 16);
}

// ---------------- accumulation for the final Kabsch (psrc -> pc) ----------------
__global__ __launch_bounds__(256) void final_acc(const float* __restrict__ psrc,
                                                 const float* __restrict__ pc,
                                                 double* __restrict__ part) {
    int b     = blockIdx.x >> 3;
    int chunk = blockIdx.x & 7;
    int i = chunk * BLK + threadIdx.x;
    const float* p = psrc + (b * NPTS + i) * 3;
    const float* q = pc   + (b * NPTS + i) * 3;
    float x = p[0], y = p[1], z = p[2];
    float qx = q[0], qy = q[1], qz = q[2];

    double v[16];
    v[0] = 0.0;
    v[1] = x;  v[2] = y;  v[3] = z;
    v[4] = qx; v[5] = qy; v[6] = qz;
    v[7]  = (double)x * qx; v[8]  = (double)x * qy; v[9]  = (double)x * qz;
    v[10] = (double)y * qx; v[11] = (double)y * qy; v[12] = (double)y * qz;
    v[13] = (double)z * qx; v[14] = (double)z * qy; v[15] = (double)z * qz;

    block_reduce_store16(v, part + (b * 8 + chunk) * 16);
}

// ---------------- 3x3 Kabsch (double, one-sided Jacobi SVD) ----------------
__device__ void kabsch3x3(const double Spq[9], const double Sp[3], const double Sq[3],
                          double R[9], double t[3]) {
    const double invN = 1.0 / (double)NPTS;
    double cs[3], ct[3];
#pragma unroll
    for (int i = 0; i < 3; ++i) { cs[i] = Sp[i] * invN; ct[i] = Sq[i] * invN; }
    double H[9];
#pragma unroll
    for (int i = 0; i < 3; ++i)
#pragma unroll
        for (int j = 0; j < 3; ++j)
            H[i * 3 + j] = Spq[i * 3 + j] - (double)NPTS * cs[i] * ct[j];

    double Bc[3][3], V[3][3];
#pragma unroll
    for (int j = 0; j < 3; ++j)
#pragma unroll
        for (int i = 0; i < 3; ++i) {
            Bc[j][i] = H[i * 3 + j];
            V[j][i]  = (i == j) ? 1.0 : 0.0;
        }
    for (int sweep = 0; sweep < 30; ++sweep) {
        bool rotated = false;
        for (int p = 0; p < 2; ++p)
            for (int q = p + 1; q < 3; ++q) {
                double app = 0, aqq = 0, apq = 0;
#pragma unroll
                for (int i = 0; i < 3; ++i) {
                    app += Bc[p][i] * Bc[p][i];
                    aqq += Bc[q][i] * Bc[q][i];
                    apq += Bc[p][i] * Bc[q][i];
                }
                if (apq * apq > 1e-60 + 1e-28 * app * aqq) {
                    rotated = true;
                    double tau = (aqq - app) / (2.0 * apq);
                    double tt  = (tau >= 0 ? 1.0 : -1.0) / (fabs(tau) + sqrt(1.0 + tau * tau));
                    double c   = 1.0 / sqrt(1.0 + tt * tt);
                    double sn  = c * tt;
#pragma unroll
                    for (int i = 0; i < 3; ++i) {
                        double bp = Bc[p][i], bq = Bc[q][i];
                        Bc[p][i] = c * bp - sn * bq;
                        Bc[q][i] = sn * bp + c * bq;
                        double vp = V[p][i], vq = V[q][i];
                        V[p][i] = c * vp - sn * vq;
                        V[q][i] = sn * vp + c * vq;
                    }
                }
            }
        if (!rotated) break;
    }
    double sv[3], U[3][3];
#pragma unroll
    for (int j = 0; j < 3; ++j) {
        sv[j] = sqrt(Bc[j][0] * Bc[j][0] + Bc[j][1] * Bc[j][1] + Bc[j][2] * Bc[j][2]);
        double inv = sv[j] > 0.0 ? 1.0 / sv[j] : 0.0;
#pragma unroll
        for (int i = 0; i < 3; ++i) U[j][i] = Bc[j][i] * inv;
    }
    double detH = H[0] * (H[4] * H[8] - H[5] * H[7])
                - H[1] * (H[3] * H[8] - H[5] * H[6])
                + H[2] * (H[3] * H[7] - H[4] * H[6]);
    double d = (detH >= 0.0) ? 1.0 : -1.0;
    int o[3] = {0, 1, 2};
    if (sv[o[0]] < sv[o[1]]) { int tmp = o[0]; o[0] = o[1]; o[1] = tmp; }
    if (sv[o[0]] < sv[o[2]]) { int tmp = o[0]; o[0] = o[2]; o[2] = tmp; }
    if (sv[o[1]] < sv[o[2]]) { int tmp = o[1]; o[1] = o[2]; o[2] = tmp; }
    double sg[3] = {1.0, 1.0, d};
#pragma unroll
    for (int i = 0; i < 3; ++i)
#pragma unroll
        for (int j = 0; j < 3; ++j) {
            double acc = 0.0;
#pragma unroll
            for (int k = 0; k < 3; ++k) acc += sg[k] * V[o[k]][i] * U[o[k]][j];
            R[i * 3 + j] = acc;
        }
#pragma unroll
    for (int i = 0; i < 3; ++i)
        t[i] = ct[i] - (R[i * 3 + 0] * cs[0] + R[i * 3 + 1] * cs[1] + R[i * 3 + 2] * cs[2]);
}

// ---------------- per-iteration Kabsch + convergence logic (1 wave) ----------------
__global__ __launch_bounds__(64) void kabsch_iter(const double* __restrict__ part,
                                                  float* __restrict__ err,
                                                  int* __restrict__ done,
                                                  float* __restrict__ Rt) {
    int b = threadIdx.x;
    int done_old = *done;
    double s[16];
    float errnew = 0.0f;
    if (b < NBATCH) {
#pragma unroll
        for (int k = 0; k < 16; ++k) {
            double a = 0.0;
            for (int c = 0; c < 8; ++c) a += part[(b * 8 + c) * 16 + k];
            s[k] = a;
        }
        errnew = (float)(s[0] * (1.0 / (double)NPTS));
    }
    bool conv = true;
    if (b < NBATCH) conv = fabsf(errnew - err[b]) < TOLF;
    unsigned long long m = __ballot(conv);
    bool all_conv = ((m & 0xFFull) == 0xFFull);
    int done_new = done_old | (all_conv ? 1 : 0);
    if (threadIdx.x == 0) *done = done_new;
    if (done_new) return;
    if (b < NBATCH) {
        err[b] = errnew;
        double R[9], t[3];
        kabsch3x3(&s[7], &s[1], &s[4], R, t);
        float* rt = Rt + b * 12;
#pragma unroll
        for (int k = 0; k < 9; ++k) rt[k] = (float)R[k];
#pragma unroll
        for (int k = 0; k < 3; ++k) rt[9 + k] = (float)t[k];
    }
}

// ---------------- final Kabsch -> d_out [B,3,4] ----------------
__global__ __launch_bounds__(64) void kabsch_final(const double* __restrict__ part,
                                                   float* __restrict__ out) {
    int b = threadIdx.x;
    if (b >= NBATCH) return;
    double s[16];
#pragma unroll
    for (int k = 0; k < 16; ++k) {
        double a = 0.0;
        for (int c = 0; c < 8; ++c) a += part[(b * 8 + c) * 16 + k];
        s[k] = a;
    }
    double R[9], t[3];
    kabsch3x3(&s[7], &s[1], &s[4], R, t);
    float* o = out + b * 12;
#pragma unroll
    for (int i = 0; i < 3; ++i) {
#pragma unroll
        for (int j = 0; j < 3; ++j) o[i * 4 + j] = (float)R[i * 3 + j];
        o[i * 4 + 3] = (float)t[i];
    }
}

// ---------------- apply rigid update ----------------
__global__ __launch_bounds__(256) void update_pc(float* __restrict__ pc,
                                                 const float* __restrict__ Rt,
                                                 const int* __restrict__ done) {
    if (*done) return;
    int g = blockIdx.x * blockDim.x + threadIdx.x;   // 0..16383
    int b = g >> 11;
    const float* rt = Rt + b * 12;
    float* p = pc + g * 3;
    float x = p[0], y = p[1], z = p[2];
    p[0] = rt[0] * x + rt[1] * y + rt[2] * z + rt[9];
    p[1] = rt[3] * x + rt[4] * y + rt[5] * z + rt[10];
    p[2] = rt[6] * x + rt[7] * y + rt[8] * z + rt[11];
}

extern "C" void kernel_launch(void* const* d_in, const int* in_sizes, int n_in,
                              void* d_out, int out_size, void* d_ws, size_t ws_size,
                              hipStream_t stream) {
    const float* psrc = (const float*)d_in[0];
    const float* ptgt = (const float*)d_in[1];
    float* out = (float*)d_out;

    char* ws = (char*)d_ws;
    // layout: pd (4MB float2) | part (8KB) | pc (192KB) | err | Rt | done
    size_t off = 0;
    float2* pd = (float2*)(ws + off);  off += (size_t)NBATCH * NCH * NPTS * sizeof(float2); // 4MB
    double* part = (double*)(ws + off); off += NBATCH * 8 * 16 * sizeof(double);            // 8KB
    float* pc  = (float*)(ws + off);    off += (size_t)NBATCH * NPTS * 3 * sizeof(float);   // 192KB
    float* err = (float*)(ws + off);    off += 32;
    float* Rt  = (float*)(ws + off);    off += NBATCH * 12 * sizeof(float);
    int* done  = (int*)(ws + off);

    const int nblocks = NBATCH * BLKS_PER_BATCH;  // 64

    init_ws<<<64, 256, 0, stream>>>(psrc, pc, err, done);

    for (int it = 0; it < 10; ++it) {
        nn_acc<<<NBATCH * NCH, BLK, 0, stream>>>(ptgt, pc, pd, done);
        gather_acc<<<nblocks, BLK, 0, stream>>>(ptgt, pc, pd, part, done);
        kabsch_iter<<<1, 64, 0, stream>>>(part, err, done, Rt);
        update_pc<<<nblocks, BLK, 0, stream>>>(pc, Rt, done);
    }

    final_acc<<<nblocks, BLK, 0, stream>>>(psrc, pc, part);
    kabsch_final<<<1, 64, 0, stream>>>(part, out);
}